// Round 3
// baseline (11221.019 us; speedup 1.0000x reference)
//
#include <hip/hip_runtime.h>

#define NN    4096
#define OBSN  2048
#define S1    2047
#define S2    2047
#define HID   128
#define INDIM 100
#define TOTT  (S1 + S2)
#define WTP   520   // padded LDS row stride (floats) for occ-column table

// padded LDS column maps (bank-conflict-free fragment reads)
#define HIDX(c) ((c) + 4 * ((c) >> 5))   // 128 -> 144 floats, group k base 36k
#define EIDX(c) ((c) + 4 * ((c) >> 4))   // 64  -> 80 floats,  group k base 20k

typedef float v2f __attribute__((ext_vector_type(2)));
typedef float v4f __attribute__((ext_vector_type(4)));

// Barrier WITHOUT vmcnt(0) drain: cross-thread per-step dataflow is LDS-only,
// so lgkmcnt(0) suffices; global prefetches/stores stay in flight.
__device__ __forceinline__ void bar() {
    asm volatile("s_waitcnt lgkmcnt(0)\n\ts_barrier" ::: "memory");
}

__device__ __forceinline__ float sigm(float x) {
    return 1.0f / (1.0f + __expf(-x));
}
__device__ __forceinline__ float tanh_(float x) {
    float e = __expf(2.0f * x);
    return 1.0f - 2.0f / (e + 1.0f);
}

// ---- cross-lane helpers: DPP / permlane replacements for ds-based shfl ----
#define DPPF(x, ctrl) __int_as_float(__builtin_amdgcn_update_dpp(0, __float_as_int(x), (ctrl), 0xF, 0xF, true))

// sum over quad (lane^1 then lane^2) — bit-identical tree to shfl_xor(1),(2)
__device__ __forceinline__ float qsum(float x) {
    x += DPPF(x, 0xB1);   // quad_perm [1,0,3,2] = lane^1
    x += DPPF(x, 0x4E);   // quad_perm [2,3,0,1] = lane^2
    return x;
}
// sum over lane bits 2..5 (k = lane&3 groups stay separate) — identical tree
// to shfl_xor(4),(8),(16),(32)
__device__ __forceinline__ float usum(float x) {
    x += DPPF(DPPF(x, 0x141), 0x1B);    // half_mirror ∘ quad_rev = lane^4
    x += DPPF(DPPF(x, 0x140), 0x141);   // mirror ∘ half_mirror  = lane^8
    x += __int_as_float(__builtin_amdgcn_ds_swizzle(__float_as_int(x), 0x401F)); // lane^16
    auto r = __builtin_amdgcn_permlane32_swap(__float_as_int(x), __float_as_int(x), false, false);
    return __int_as_float(r[0]) + __int_as_float(r[1]);   // x[l] + x[l^32]
}

// Exact reference-semantics cell classification (strict < both sides).
__device__ __forceinline__ unsigned long long classify(float x, float y,
                                                       const float* bx, const float* by) {
    int a = 0, b = 0, c = 0, d = 0;
#pragma unroll
    for (int j = 0; j < 7; j++) {
        a += bx[j] < x;
        b += x < bx[j];
        c += by[j] < y;
        d += y < by[j];
    }
    if (a >= 1 && a <= 6 && (a + b) == 7 && c >= 1 && c <= 6 && (c + d) == 7)
        return 1ull << ((a - 1) * 6 + (c - 1));
    return 0ull;
}

__device__ __forceinline__ float hsum8(const float* p8) {
    const v4f a = ((const v4f*)p8)[0];
    const v4f b = ((const v4f*)p8)[1];
    return ((a.x + a.y) + (a.z + a.w)) + ((b.x + b.y) + (b.z + b.w));
}

// ---------- kernel 1: phase-1 occupancy masks (parallel over t) ----------
__global__ __launch_bounds__(256) void k_occ1(const float* __restrict__ obs,
                                              const float* __restrict__ oth,
                                              unsigned long long* __restrict__ occm) {
    const int t = blockIdx.x;
    const int slice = t + 1;
    const float cx = obs[slice * 2 + 0];
    const float cy = obs[slice * 2 + 1];
    const float CST[7] = {-1.5f, -1.0f, -0.5f, 0.0f, 0.5f, 1.0f, 1.5f};
    float bx[7], by[7];
#pragma unroll
    for (int j = 0; j < 7; j++) { bx[j] = CST[j] + cx; by[j] = CST[j] + cy; }

    const float2* p = (const float2*)(oth + (size_t)slice * NN * 2);
    unsigned long long m = 0ull;
#pragma unroll 4
    for (int i = 0; i < 16; i++) {
        float2 q = p[i * 256 + threadIdx.x];
        if (q.x > bx[0] && q.x < bx[6] && q.y > by[0] && q.y < by[6])
            m |= classify(q.x, q.y, bx, by);
    }
#pragma unroll
    for (int off = 32; off > 0; off >>= 1) m |= __shfl_down(m, off);
    __shared__ unsigned long long sm[4];
    if ((threadIdx.x & 63) == 0) sm[threadIdx.x >> 6] = m;
    __syncthreads();
    if (threadIdx.x == 0) occm[t] = sm[0] | sm[1] | sm[2] | sm[3];
}

// ---------- kernel 2: transpose occ columns of W_ih into [36][512] ----------
__global__ void k_tr(const float* __restrict__ W_ih, float* __restrict__ WT) {
    WT[blockIdx.x * 512 + threadIdx.x] = W_ih[threadIdx.x * INDIM + 64 + blockIdx.x];
}

// ---------- kernel 3: phase-1 gate preactivation G1[t][512] ----------
__global__ __launch_bounds__(256) void k_g1(const float* __restrict__ obs,
                                            const float* __restrict__ W_emb,
                                            const float* __restrict__ b_emb,
                                            const float* __restrict__ W_ih,
                                            const float* __restrict__ b_ih,
                                            const float* __restrict__ b_hh,
                                            const unsigned long long* __restrict__ occm,
                                            float* __restrict__ G1) {
    const int t = blockIdx.x;
    const int tid = threadIdx.x;
    __shared__ __align__(16) float e[64];
    const float d0 = obs[(t + 1) * 2 + 0] - obs[t * 2 + 0];
    const float d1 = obs[(t + 1) * 2 + 1] - obs[t * 2 + 1];
    if (tid < 64) {
        float v = W_emb[tid * 2 + 0] * d0 + W_emb[tid * 2 + 1] * d1 + b_emb[tid];
        e[tid] = v > 0.0f ? v : 0.0f;
    }
    __syncthreads();
    const unsigned long long m = occm[t];
#pragma unroll
    for (int rr = 0; rr < 2; rr++) {
        const int r = tid + rr * 256;
        const float* wr = W_ih + r * INDIM;
        float s = b_ih[r] + b_hh[r];
        float4 acc = {0.f, 0.f, 0.f, 0.f};
        const float4* w4 = (const float4*)wr;
        const float4* e4 = (const float4*)e;
#pragma unroll
        for (int q = 0; q < 16; q++) {
            float4 w = w4[q], ev = e4[q];
            acc.x += w.x * ev.x; acc.y += w.y * ev.y;
            acc.z += w.z * ev.z; acc.w += w.w * ev.w;
        }
        s += (acc.x + acc.y) + (acc.z + acc.w);
        unsigned long long mm = m;
        while (mm) {
            int j = __ffsll((long long)mm) - 1;
            mm &= mm - 1;
            s += wr[64 + j];
        }
        G1[t * 512 + r] = s;
    }
}

// ---------- kernel 4: sequential LSTM ----------
// 512 threads = 8 waves. Thread owns unit u = wv*16 + (lane>>2), gate rows
// {u+128g}, h-cols [32k,32k+32), emb-cols [16k,16k+16) with k = lane&3.
// This round: padded hbuf/e_lds (kills the 4-way ds_read_b128 bank conflict),
// SALU-extracted occ-column indices + batched dummy-padded LDS loads (removes
// per-iteration lgkm waits from the og gather), max-abs superset box filter
// (classify stays exact -> identical mask bits), 2-deep G1 prefetch.
__global__ __launch_bounds__(512, 2) void k_seq(const float* __restrict__ obs,
                                                const float* __restrict__ oth,
                                                const float* __restrict__ W_emb,
                                                const float* __restrict__ b_emb,
                                                const float* __restrict__ W_ih,
                                                const float* __restrict__ b_ih,
                                                const float* __restrict__ W_hh,
                                                const float* __restrict__ b_hh,
                                                const float* __restrict__ W_out,
                                                const float* __restrict__ b_out,
                                                const float* __restrict__ G1,
                                                const float* __restrict__ WT,
                                                float* __restrict__ hist) {
    const int tid  = threadIdx.x;
    const int wv   = tid >> 6;
    const int lane = tid & 63;
    const int u    = wv * 16 + (lane >> 2);
    const int k    = lane & 3;

    // --- persistent W_hh fragment: rows u+128g, cols [32k, 32k+32) ---
    v2f whh[4][16];
#pragma unroll
    for (int g = 0; g < 4; g++) {
        const v2f* src = (const v2f*)(W_hh + (u + 128 * g) * HID + 32 * k);
#pragma unroll
        for (int j = 0; j < 16; j++) whh[g][j] = src[j];
    }

    const float won0 = W_out[u];            // out dim 0 (feedback)
    const float won1 = W_out[HID + u];      // out dim 1 (feedback)
    const float bo0 = b_out[0], bo1 = b_out[1];
    float we0 = 0.f, we1 = 0.f, be = 0.f;
    if (tid < 64) { we0 = W_emb[tid * 2]; we1 = W_emb[tid * 2 + 1]; be = b_emb[tid]; }
    const float obsA0 = obs[(S1 - 1) * 2], obsA1 = obs[(S1 - 1) * 2 + 1];
    const float obsB0 = obs[S1 * 2],       obsB1 = obs[S1 * 2 + 1];

    __shared__ __align__(16) float WTl[37 * WTP];   // occ columns + zero row 36
    __shared__ __align__(16) float hbufP[2][144];   // padded h (HIDX map)
    __shared__ __align__(16) float e_ldsP[80];      // padded e (EIDX map)
    __shared__ __align__(16) float redn[2][8];
    __shared__ unsigned int mword[4];               // [slot][lo/hi]

    // stage WT (global, L2-warm from k_tr) into LDS; zero the dummy row
    for (int i = tid; i < 36 * 512; i += 512)
        WTl[(i >> 9) * WTP + (i & 511)] = WT[i];
    WTl[36 * WTP + tid] = 0.0f;
    if (tid < 4) mword[tid] = 0u;
    if (tid < HID) hbufP[0][HIDX(tid)] = 0.0f;
    float c = 0.0f;
    float p1x = 0.f, p1y = 0.f, p2x = 0.f, p2y = 0.f;
    int p = 0;
    __syncthreads();

    // 2-deep G1 prefetch (HBM-miss latency ~900cy > 1 phase-1 step)
    v4f g1_cur, g1_nxt;
    {
        const float* gp = G1 + u;
        g1_cur.x = gp[0]; g1_cur.y = gp[128]; g1_cur.z = gp[256]; g1_cur.w = gp[384];
        const float* gq = G1 + 512 + u;
        g1_nxt.x = gq[0]; g1_nxt.y = gq[128]; g1_nxt.z = gq[256]; g1_nxt.w = gq[384];
    }

    // =============== phase 1: 1 barrier/step ===============
    for (int t = 0; t < S1; ++t) {
        const v4f cur = g1_cur;
        v4f g1_fut;
        {
            const int tf = (t + 2 < S1) ? t + 2 : S1 - 1;
            const float* gp = G1 + tf * 512 + u;
            g1_fut.x = gp[0]; g1_fut.y = gp[128]; g1_fut.z = gp[256]; g1_fut.w = gp[384];
        }

        v2f a0 = {0.f, 0.f}, a1 = {0.f, 0.f}, a2 = {0.f, 0.f}, a3 = {0.f, 0.f};
        const v4f* h4 = (const v4f*)(&hbufP[p][36 * k]);
#pragma unroll
        for (int q = 0; q < 8; q++) {
            const v4f hv = h4[q];
            const v2f hl = hv.xy, hh2 = hv.zw;
            a0 = whh[0][2*q] * hl + a0;  a0 = whh[0][2*q+1] * hh2 + a0;
            a1 = whh[1][2*q] * hl + a1;  a1 = whh[1][2*q+1] * hh2 + a1;
            a2 = whh[2][2*q] * hl + a2;  a2 = whh[2][2*q+1] * hh2 + a2;
            a3 = whh[3][2*q] * hl + a3;  a3 = whh[3][2*q+1] * hh2 + a3;
        }
        float pg0 = (a0.x + a0.y) + ((k == 0) ? cur.x : 0.0f);
        float pg1 = (a1.x + a1.y) + ((k == 0) ? cur.y : 0.0f);
        float pg2 = (a2.x + a2.y) + ((k == 0) ? cur.z : 0.0f);
        float pg3 = (a3.x + a3.y) + ((k == 0) ? cur.w : 0.0f);
        pg0 = qsum(pg0); pg1 = qsum(pg1); pg2 = qsum(pg2); pg3 = qsum(pg3);

        const float gi = sigm(pg0), gf = sigm(pg1);
        const float gG = tanh_(pg2), go = sigm(pg3);
        c = gf * c + gi * gG;
        const float h = go * tanh_(c);
        if (k == 0) {
            hbufP[p ^ 1][HIDX(u)] = h;
            hist[(size_t)t * HID + u] = h;    // fire-and-forget (epilogue reads)
        }

        if (t >= S1 - 2) {     // uniform branch: handoff positions to all threads
            float pd = (k == 0 ? won0 : (k == 1 ? won1 : 0.0f)) * h;
            pd = usum(pd);
            if (lane < 2) redn[lane][wv] = pd;
            bar();
            const float n0 = hsum8(redn[0]) + bo0;
            const float n1 = hsum8(redn[1]) + bo1;
            if (t == S1 - 2) { p1x = obsA0 + n0; p1y = obsA1 + n1; }
            else             { p2x = obsB0 + n0; p2y = obsB1 + n1; }
        }
        bar();
        p ^= 1;
        g1_cur = g1_nxt; g1_nxt = g1_fut;
    }

    // --- phase-2-only weights loaded here to split register lifetimes ---
    v2f wie[4][8];
#pragma unroll
    for (int g = 0; g < 4; g++) {
        const v2f* src = (const v2f*)(W_ih + (u + 128 * g) * INDIM + 16 * k);
#pragma unroll
        for (int j = 0; j < 8; j++) wie[g][j] = src[j];
    }
    float biasg[4];
#pragma unroll
    for (int g = 0; g < 4; g++) biasg[g] = b_ih[u + 128 * g] + b_hh[u + 128 * g];

    float pcx = p2x, pcy = p2y;
    float dx = p2x - p1x, dy = p2y - p1y;

    v4f nb[4];   // 8 neighbor points per thread
    {
        const v4f* s0 = (const v4f*)(oth + (size_t)OBSN * NN * 2);
#pragma unroll
        for (int i = 0; i < 4; i++) nb[i] = s0[i * 512 + tid];
    }
    if (tid < 64) {   // e for s=0; visible after first bar (B1)
        float v = we0 * dx + we1 * dy + be;
        e_ldsP[EIDX(tid)] = v > 0.0f ? v : 0.0f;
    }
    const float CST[7] = {-1.5f, -1.0f, -0.5f, 0.0f, 0.5f, 1.0f, 1.5f};
    int sl = 0;   // mask double-buffer slot

    // =============== phase 2: 2 barriers/step ===============
    for (int s = 0; s < S2; ++s) {
        float bx[7], by[7];
#pragma unroll
        for (int j = 0; j < 7; j++) { bx[j] = CST[j] + pcx; by[j] = CST[j] + pcy; }

        // box filter: max(|dx|,|dy|) < 1.6 is a guaranteed float superset of
        // the exact box; classify() redoes the exact reference compares.
        unsigned long long m = 0ull;
#pragma unroll
        for (int i = 0; i < 4; i++) {
            const v4f q = nb[i];
            const float tA = fmaxf(fabsf(q.x - pcx), fabsf(q.y - pcy));
            const float tB = fmaxf(fabsf(q.z - pcx), fabsf(q.w - pcy));
            if (tA < 1.6f) m |= classify(q.x, q.y, bx, by);
            if (tB < 1.6f) m |= classify(q.z, q.w, bx, by);
        }
        // sparse union: in-box points are rare -> almost all lanes skip
        if (m) {
            const unsigned int lo = (unsigned int)m;
            const unsigned int hi = (unsigned int)(m >> 32);
            if (lo) atomicOr(&mword[sl * 2 + 0], lo);
            if (hi) atomicOr(&mword[sl * 2 + 1], hi);
        }
        {   // next-slice prefetch; lgkm-only barriers never drain it
            const int sn = (s + 1 < S2) ? s + 1 : s;
            const v4f* pf = (const v4f*)(oth + (size_t)(OBSN + sn) * NN * 2);
#pragma unroll
            for (int i = 0; i < 4; i++) nb[i] = pf[i * 512 + tid];
        }
        bar();   // B1: union mask + e_lds ready

        const unsigned int mlo_v = mword[sl * 2 + 0];
        const unsigned int mhi_v = mword[sl * 2 + 1];
        // zero the OTHER slot for step s+1 (its last readers were 2 barriers ago)
        if (tid == 0) { mword[(sl ^ 1) * 2] = 0u; mword[(sl ^ 1) * 2 + 1] = 0u; }

        // union mask is wave-uniform -> SGPR; extract first 12 set bits on the
        // SALU pipe (free), 3 indices per k-lane, dummy row 36 pads short lists.
        unsigned long long um =
            ((unsigned long long)(unsigned int)__builtin_amdgcn_readfirstlane((int)mhi_v) << 32) |
            (unsigned long long)(unsigned int)__builtin_amdgcn_readfirstlane((int)mlo_v);
        int e0, e1, e2, e3, e4i, e5, e6, e7, e8, e9, e10, e11;
#define EXT(v) v = um ? (int)(__ffsll((long long)um) - 1) : 36; um &= um - 1;
        EXT(e0) EXT(e1) EXT(e2) EXT(e3) EXT(e4i) EXT(e5)
        EXT(e6) EXT(e7) EXT(e8) EXT(e9) EXT(e10) EXT(e11)
#undef EXT
        const int j0 = (k == 0) ? e0 : (k == 1) ? e1  : (k == 2) ? e2  : e3;
        const int j1 = (k == 0) ? e4i: (k == 1) ? e5  : (k == 2) ? e6  : e7;
        const int j2 = (k == 0) ? e8 : (k == 1) ? e9  : (k == 2) ? e10 : e11;
        const float* w0 = WTl + j0 * WTP + u;
        const float* w1 = WTl + j1 * WTP + u;
        const float* w2 = WTl + j2 * WTP + u;
        const float c00 = w0[0], c01 = w0[128], c02 = w0[256], c03 = w0[384];
        const float c10 = w1[0], c11 = w1[128], c12 = w1[256], c13 = w1[384];
        const float c20 = w2[0], c21 = w2[128], c22 = w2[256], c23 = w2[384];

        // dots run while the 12 og loads are in flight
        v2f a0 = {0.f, 0.f}, a1 = {0.f, 0.f}, a2 = {0.f, 0.f}, a3 = {0.f, 0.f};
        {
            const v4f* e4 = (const v4f*)(&e_ldsP[20 * k]);
#pragma unroll
            for (int q = 0; q < 4; q++) {
                const v4f ev = e4[q];
                const v2f el = ev.xy, eh = ev.zw;
                a0 = wie[0][2*q] * el + a0;  a0 = wie[0][2*q+1] * eh + a0;
                a1 = wie[1][2*q] * el + a1;  a1 = wie[1][2*q+1] * eh + a1;
                a2 = wie[2][2*q] * el + a2;  a2 = wie[2][2*q+1] * eh + a2;
                a3 = wie[3][2*q] * el + a3;  a3 = wie[3][2*q+1] * eh + a3;
            }
            const v4f* h4 = (const v4f*)(&hbufP[p][36 * k]);
#pragma unroll
            for (int q = 0; q < 8; q++) {
                const v4f hv = h4[q];
                const v2f hl = hv.xy, hh2 = hv.zw;
                a0 = whh[0][2*q] * hl + a0;  a0 = whh[0][2*q+1] * hh2 + a0;
                a1 = whh[1][2*q] * hl + a1;  a1 = whh[1][2*q+1] * hh2 + a1;
                a2 = whh[2][2*q] * hl + a2;  a2 = whh[2][2*q+1] * hh2 + a2;
                a3 = whh[3][2*q] * hl + a3;  a3 = whh[3][2*q+1] * hh2 + a3;
            }
        }

        // fold og in the SAME ascending own-stripe order as before (+0.0f pads)
        float og0 = (k == 0) ? biasg[0] : 0.0f;
        float og1 = (k == 0) ? biasg[1] : 0.0f;
        float og2 = (k == 0) ? biasg[2] : 0.0f;
        float og3 = (k == 0) ? biasg[3] : 0.0f;
        og0 += c00; og0 += c10; og0 += c20;
        og1 += c01; og1 += c11; og1 += c21;
        og2 += c02; og2 += c12; og2 += c22;
        og3 += c03; og3 += c13; og3 += c23;
        if (um) {   // rare: >12 occupied cells; uniform branch, appended order
            unsigned long long mm2 = um;
            int idx = 12;
            while (mm2) {
                const int j = __ffsll((long long)mm2) - 1;
                mm2 &= mm2 - 1;
                if ((idx & 3) == k) {
                    const float* wc = WTl + j * WTP + u;
                    og0 += wc[0];
                    og1 += wc[128];
                    og2 += wc[256];
                    og3 += wc[384];
                }
                idx++;
            }
        }

        float pg0 = og0 + (a0.x + a0.y);
        float pg1 = og1 + (a1.x + a1.y);
        float pg2 = og2 + (a2.x + a2.y);
        float pg3 = og3 + (a3.x + a3.y);
        pg0 = qsum(pg0); pg1 = qsum(pg1); pg2 = qsum(pg2); pg3 = qsum(pg3);

        const float gi = sigm(pg0), gf = sigm(pg1);
        const float gG = tanh_(pg2), go = sigm(pg3);
        c = gf * c + gi * gG;
        const float h = go * tanh_(c);
        if (k == 0) {
            hbufP[p ^ 1][HIDX(u)] = h;
            hist[(size_t)(S1 + s) * HID + u] = h;
        }

        float pd = (k == 0 ? won0 : (k == 1 ? won1 : 0.0f)) * h;
        pd = usum(pd);
        if (lane < 2) redn[lane][wv] = pd;
        bar();   // B2: h + redn ready

        const float n0 = hsum8(redn[0]) + bo0;
        const float n1 = hsum8(redn[1]) + bo1;
        dx = n0; dy = n1;
        pcx += n0; pcy += n1;
        if (tid < 64) {   // e for s+1; ordered vs this step's readers by B2
            float v = we0 * dx + we1 * dy + be;
            e_ldsP[EIDX(tid)] = v > 0.0f ? v : 0.0f;
        }
        p ^= 1; sl ^= 1;
    }
}

// ---------- kernel 5: parallel epilogue — out[t] = hist[t] @ W_out^T + b ----------
__global__ __launch_bounds__(64) void k_out(const float* __restrict__ hist,
                                            const float* __restrict__ W_out,
                                            const float* __restrict__ b_out,
                                            float* __restrict__ out) {
    const int t = blockIdx.x;
    const int l = threadIdx.x;
    const float h0 = hist[(size_t)t * HID + l];
    const float h1 = hist[(size_t)t * HID + 64 + l];
#pragma unroll
    for (int d = 0; d < 5; ++d) {
        float pz = W_out[d * HID + l] * h0 + W_out[d * HID + 64 + l] * h1;
#pragma unroll
        for (int off = 1; off < 64; off <<= 1) pz += __shfl_xor(pz, off);
        if (l == 0) out[t * 5 + d] = pz + b_out[d];
    }
}

// ---------- launcher ----------
extern "C" void kernel_launch(void* const* d_in, const int* in_sizes, int n_in,
                              void* d_out, int out_size, void* d_ws, size_t ws_size,
                              hipStream_t stream) {
    const float* obs   = (const float*)d_in[0];
    const float* oth   = (const float*)d_in[1];
    const float* W_emb = (const float*)d_in[2];
    const float* b_emb = (const float*)d_in[3];
    const float* W_ih  = (const float*)d_in[4];
    const float* b_ih  = (const float*)d_in[5];
    const float* W_hh  = (const float*)d_in[6];
    const float* b_hh  = (const float*)d_in[7];
    const float* W_out = (const float*)d_in[8];
    const float* b_out = (const float*)d_in[9];
    float* out = (float*)d_out;

    unsigned long long* occm = (unsigned long long*)d_ws;
    float* G1   = (float*)((char*)d_ws + 16384);
    float* WT   = (float*)((char*)d_ws + 16384 + (size_t)S1 * 512 * 4);
    float* hist = (float*)((char*)d_ws + 16384 + (size_t)S1 * 512 * 4 + (size_t)36 * 512 * 4);

    k_occ1<<<S1, 256, 0, stream>>>(obs, oth, occm);
    k_tr<<<36, 512, 0, stream>>>(W_ih, WT);
    k_g1<<<S1, 256, 0, stream>>>(obs, W_emb, b_emb, W_ih, b_ih, b_hh, occm, G1);
    k_seq<<<1, 512, 0, stream>>>(obs, oth, W_emb, b_emb, W_ih, b_ih, W_hh, b_hh,
                                 W_out, b_out, G1, WT, hist);
    k_out<<<TOTT, 64, 0, stream>>>(hist, W_out, b_out, out);
}

// Round 4
// 8074.014 us; speedup vs baseline: 1.3898x; 1.3898x over previous
//
#include <hip/hip_runtime.h>

#define NN    4096
#define OBSN  2048
#define S1    2047
#define S2    2047
#define HID   128
#define INDIM 100
#define TOTT  (S1 + S2)
#define WTP   520   // padded LDS row stride (floats) for occ-column table

// padded LDS column maps (bank-conflict-free fragment reads)
#define HIDX(c) ((c) + 4 * ((c) >> 5))   // 128 -> 144 floats, group k base 36k
#define EIDX(c) ((c) + 4 * ((c) >> 4))   // 64  -> 80 floats,  group k base 20k

typedef float v2f __attribute__((ext_vector_type(2)));
typedef float v4f __attribute__((ext_vector_type(4)));

// Barrier WITHOUT vmcnt(0) drain: cross-thread per-step dataflow is LDS-only,
// so lgkmcnt(0) suffices; global prefetches/stores stay in flight.
__device__ __forceinline__ void bar() {
    asm volatile("s_waitcnt lgkmcnt(0)\n\ts_barrier" ::: "memory");
}

__device__ __forceinline__ float sigm(float x) {
    return 1.0f / (1.0f + __expf(-x));
}
__device__ __forceinline__ float tanh_(float x) {
    float e = __expf(2.0f * x);
    return 1.0f - 2.0f / (e + 1.0f);
}

// ---- cross-lane helpers: DPP / permlane replacements for ds-based shfl ----
#define DPPF(x, ctrl) __int_as_float(__builtin_amdgcn_update_dpp(0, __float_as_int(x), (ctrl), 0xF, 0xF, true))

// sum over quad (lane^1 then lane^2) — bit-identical tree to shfl_xor(1),(2)
__device__ __forceinline__ float qsum(float x) {
    x += DPPF(x, 0xB1);   // quad_perm [1,0,3,2] = lane^1
    x += DPPF(x, 0x4E);   // quad_perm [2,3,0,1] = lane^2
    return x;
}
// sum over lane bits 2..5 (k = lane&3 groups stay separate) — identical tree
// to shfl_xor(4),(8),(16),(32)
__device__ __forceinline__ float usum(float x) {
    x += DPPF(DPPF(x, 0x141), 0x1B);    // half_mirror ∘ quad_rev = lane^4
    x += DPPF(DPPF(x, 0x140), 0x141);   // mirror ∘ half_mirror  = lane^8
    x += __int_as_float(__builtin_amdgcn_ds_swizzle(__float_as_int(x), 0x401F)); // lane^16
    auto r = __builtin_amdgcn_permlane32_swap(__float_as_int(x), __float_as_int(x), false, false);
    return __int_as_float(r[0]) + __int_as_float(r[1]);   // x[l] + x[l^32]
}

// Exact reference-semantics cell classification (strict < both sides).
__device__ __forceinline__ unsigned long long classify(float x, float y,
                                                       const float* bx, const float* by) {
    int a = 0, b = 0, c = 0, d = 0;
#pragma unroll
    for (int j = 0; j < 7; j++) {
        a += bx[j] < x;
        b += x < bx[j];
        c += by[j] < y;
        d += y < by[j];
    }
    if (a >= 1 && a <= 6 && (a + b) == 7 && c >= 1 && c <= 6 && (c + d) == 7)
        return 1ull << ((a - 1) * 6 + (c - 1));
    return 0ull;
}

__device__ __forceinline__ float hsum8(const float* p8) {
    const v4f a = ((const v4f*)p8)[0];
    const v4f b = ((const v4f*)p8)[1];
    return ((a.x + a.y) + (a.z + a.w)) + ((b.x + b.y) + (b.z + b.w));
}

// ---------- kernel 1: phase-1 occupancy masks (parallel over t) ----------
__global__ __launch_bounds__(256) void k_occ1(const float* __restrict__ obs,
                                              const float* __restrict__ oth,
                                              unsigned long long* __restrict__ occm) {
    const int t = blockIdx.x;
    const int slice = t + 1;
    const float cx = obs[slice * 2 + 0];
    const float cy = obs[slice * 2 + 1];
    const float CST[7] = {-1.5f, -1.0f, -0.5f, 0.0f, 0.5f, 1.0f, 1.5f};
    float bx[7], by[7];
#pragma unroll
    for (int j = 0; j < 7; j++) { bx[j] = CST[j] + cx; by[j] = CST[j] + cy; }

    const float2* p = (const float2*)(oth + (size_t)slice * NN * 2);
    unsigned long long m = 0ull;
#pragma unroll 4
    for (int i = 0; i < 16; i++) {
        float2 q = p[i * 256 + threadIdx.x];
        if (q.x > bx[0] && q.x < bx[6] && q.y > by[0] && q.y < by[6])
            m |= classify(q.x, q.y, bx, by);
    }
#pragma unroll
    for (int off = 32; off > 0; off >>= 1) m |= __shfl_down(m, off);
    __shared__ unsigned long long sm[4];
    if ((threadIdx.x & 63) == 0) sm[threadIdx.x >> 6] = m;
    __syncthreads();
    if (threadIdx.x == 0) occm[t] = sm[0] | sm[1] | sm[2] | sm[3];
}

// ---------- kernel 2: transpose occ columns of W_ih into [36][512] ----------
__global__ void k_tr(const float* __restrict__ W_ih, float* __restrict__ WT) {
    WT[blockIdx.x * 512 + threadIdx.x] = W_ih[threadIdx.x * INDIM + 64 + blockIdx.x];
}

// ---------- kernel 3: phase-1 gate preactivation G1[t][512] ----------
__global__ __launch_bounds__(256) void k_g1(const float* __restrict__ obs,
                                            const float* __restrict__ W_emb,
                                            const float* __restrict__ b_emb,
                                            const float* __restrict__ W_ih,
                                            const float* __restrict__ b_ih,
                                            const float* __restrict__ b_hh,
                                            const unsigned long long* __restrict__ occm,
                                            float* __restrict__ G1) {
    const int t = blockIdx.x;
    const int tid = threadIdx.x;
    __shared__ __align__(16) float e[64];
    const float d0 = obs[(t + 1) * 2 + 0] - obs[t * 2 + 0];
    const float d1 = obs[(t + 1) * 2 + 1] - obs[t * 2 + 1];
    if (tid < 64) {
        float v = W_emb[tid * 2 + 0] * d0 + W_emb[tid * 2 + 1] * d1 + b_emb[tid];
        e[tid] = v > 0.0f ? v : 0.0f;
    }
    __syncthreads();
    const unsigned long long m = occm[t];
#pragma unroll
    for (int rr = 0; rr < 2; rr++) {
        const int r = tid + rr * 256;
        const float* wr = W_ih + r * INDIM;
        float s = b_ih[r] + b_hh[r];
        float4 acc = {0.f, 0.f, 0.f, 0.f};
        const float4* w4 = (const float4*)wr;
        const float4* e4 = (const float4*)e;
#pragma unroll
        for (int q = 0; q < 16; q++) {
            float4 w = w4[q], ev = e4[q];
            acc.x += w.x * ev.x; acc.y += w.y * ev.y;
            acc.z += w.z * ev.z; acc.w += w.w * ev.w;
        }
        s += (acc.x + acc.y) + (acc.z + acc.w);
        unsigned long long mm = m;
        while (mm) {
            int j = __ffsll((long long)mm) - 1;
            mm &= mm - 1;
            s += wr[64 + j];
        }
        G1[t * 512 + r] = s;
    }
}

// ---------- kernel 4: sequential LSTM ----------
// 512 threads = 8 waves. Thread owns unit u = wv*16 + (lane>>2), gate rows
// {u+128g}, h-cols [32k,32k+32), emb-cols [16k,16k+16) with k = lane&3.
// BISECT ROUND: exact round-1 structure (og while-loop, exact box test,
// 1-deep G1 prefetch) + ONLY the padded hbufP/e_ldsP column maps that
// removed 85% of SQ_LDS_BANK_CONFLICT in round 3.
__global__ __launch_bounds__(512, 2) void k_seq(const float* __restrict__ obs,
                                                const float* __restrict__ oth,
                                                const float* __restrict__ W_emb,
                                                const float* __restrict__ b_emb,
                                                const float* __restrict__ W_ih,
                                                const float* __restrict__ b_ih,
                                                const float* __restrict__ W_hh,
                                                const float* __restrict__ b_hh,
                                                const float* __restrict__ W_out,
                                                const float* __restrict__ b_out,
                                                const float* __restrict__ G1,
                                                const float* __restrict__ WT,
                                                float* __restrict__ hist) {
    const int tid  = threadIdx.x;
    const int wv   = tid >> 6;
    const int lane = tid & 63;
    const int u    = wv * 16 + (lane >> 2);
    const int k    = lane & 3;

    // --- persistent W_hh fragment: rows u+128g, cols [32k, 32k+32) ---
    v2f whh[4][16];
#pragma unroll
    for (int g = 0; g < 4; g++) {
        const v2f* src = (const v2f*)(W_hh + (u + 128 * g) * HID + 32 * k);
#pragma unroll
        for (int j = 0; j < 16; j++) whh[g][j] = src[j];
    }

    const float won0 = W_out[u];            // out dim 0 (feedback)
    const float won1 = W_out[HID + u];      // out dim 1 (feedback)
    const float bo0 = b_out[0], bo1 = b_out[1];
    float we0 = 0.f, we1 = 0.f, be = 0.f;
    if (tid < 64) { we0 = W_emb[tid * 2]; we1 = W_emb[tid * 2 + 1]; be = b_emb[tid]; }
    const float obsA0 = obs[(S1 - 1) * 2], obsA1 = obs[(S1 - 1) * 2 + 1];
    const float obsB0 = obs[S1 * 2],       obsB1 = obs[S1 * 2 + 1];

    __shared__ __align__(16) float WTl[36 * WTP];   // occ columns, padded rows
    __shared__ __align__(16) float hbufP[2][144];   // padded h (HIDX map)
    __shared__ __align__(16) float e_ldsP[80];      // padded e (EIDX map)
    __shared__ __align__(16) float redn[2][8];
    __shared__ unsigned int mword[4];               // [slot][lo/hi]

    // stage WT (global, L2-warm from k_tr) into LDS
    for (int i = tid; i < 36 * 512; i += 512)
        WTl[(i >> 9) * WTP + (i & 511)] = WT[i];
    if (tid < 4) mword[tid] = 0u;
    if (tid < HID) hbufP[0][HIDX(tid)] = 0.0f;
    float c = 0.0f;
    float p1x = 0.f, p1y = 0.f, p2x = 0.f, p2y = 0.f;
    int p = 0;
    __syncthreads();

    // G1 prefetch for t=0 (rows u+128g; same addr across the quad -> merged)
    v4f g1v;
    {
        const float* gp = G1 + u;
        g1v.x = gp[0]; g1v.y = gp[128]; g1v.z = gp[256]; g1v.w = gp[384];
    }

    // =============== phase 1: 1 barrier/step ===============
    for (int t = 0; t < S1; ++t) {
        const v4f cur = g1v;
        const int tn = (t + 1 < S1) ? t + 1 : t;
        {
            const float* gp = G1 + tn * 512 + u;
            g1v.x = gp[0]; g1v.y = gp[128]; g1v.z = gp[256]; g1v.w = gp[384];
        }

        v2f a0 = {0.f, 0.f}, a1 = {0.f, 0.f}, a2 = {0.f, 0.f}, a3 = {0.f, 0.f};
        const v4f* h4 = (const v4f*)(&hbufP[p][36 * k]);
#pragma unroll
        for (int q = 0; q < 8; q++) {
            const v4f hv = h4[q];
            const v2f hl = hv.xy, hh2 = hv.zw;
            a0 = whh[0][2*q] * hl + a0;  a0 = whh[0][2*q+1] * hh2 + a0;
            a1 = whh[1][2*q] * hl + a1;  a1 = whh[1][2*q+1] * hh2 + a1;
            a2 = whh[2][2*q] * hl + a2;  a2 = whh[2][2*q+1] * hh2 + a2;
            a3 = whh[3][2*q] * hl + a3;  a3 = whh[3][2*q+1] * hh2 + a3;
        }
        float pg0 = (a0.x + a0.y) + ((k == 0) ? cur.x : 0.0f);
        float pg1 = (a1.x + a1.y) + ((k == 0) ? cur.y : 0.0f);
        float pg2 = (a2.x + a2.y) + ((k == 0) ? cur.z : 0.0f);
        float pg3 = (a3.x + a3.y) + ((k == 0) ? cur.w : 0.0f);
        pg0 = qsum(pg0); pg1 = qsum(pg1); pg2 = qsum(pg2); pg3 = qsum(pg3);

        const float gi = sigm(pg0), gf = sigm(pg1);
        const float gG = tanh_(pg2), go = sigm(pg3);
        c = gf * c + gi * gG;
        const float h = go * tanh_(c);
        if (k == 0) {
            hbufP[p ^ 1][HIDX(u)] = h;
            hist[(size_t)t * HID + u] = h;    // fire-and-forget (epilogue reads)
        }

        if (t >= S1 - 2) {     // uniform branch: handoff positions to all threads
            float pd = (k == 0 ? won0 : (k == 1 ? won1 : 0.0f)) * h;
            pd = usum(pd);
            if (lane < 2) redn[lane][wv] = pd;
            bar();
            const float n0 = hsum8(redn[0]) + bo0;
            const float n1 = hsum8(redn[1]) + bo1;
            if (t == S1 - 2) { p1x = obsA0 + n0; p1y = obsA1 + n1; }
            else             { p2x = obsB0 + n0; p2y = obsB1 + n1; }
        }
        bar();
        p ^= 1;
    }

    // --- phase-2-only weights loaded here to split register lifetimes ---
    v2f wie[4][8];
#pragma unroll
    for (int g = 0; g < 4; g++) {
        const v2f* src = (const v2f*)(W_ih + (u + 128 * g) * INDIM + 16 * k);
#pragma unroll
        for (int j = 0; j < 8; j++) wie[g][j] = src[j];
    }
    float biasg[4];
#pragma unroll
    for (int g = 0; g < 4; g++) biasg[g] = b_ih[u + 128 * g] + b_hh[u + 128 * g];

    float pcx = p2x, pcy = p2y;
    float dx = p2x - p1x, dy = p2y - p1y;

    v4f nb[4];   // 8 neighbor points per thread
    {
        const v4f* s0 = (const v4f*)(oth + (size_t)OBSN * NN * 2);
#pragma unroll
        for (int i = 0; i < 4; i++) nb[i] = s0[i * 512 + tid];
    }
    if (tid < 64) {   // e for s=0; visible after first bar (B1)
        float v = we0 * dx + we1 * dy + be;
        e_ldsP[EIDX(tid)] = v > 0.0f ? v : 0.0f;
    }
    const float CST[7] = {-1.5f, -1.0f, -0.5f, 0.0f, 0.5f, 1.0f, 1.5f};
    int sl = 0;   // mask double-buffer slot

    // =============== phase 2: 2 barriers/step ===============
    for (int s = 0; s < S2; ++s) {
        float bx[7], by[7];
#pragma unroll
        for (int j = 0; j < 7; j++) { bx[j] = CST[j] + pcx; by[j] = CST[j] + pcy; }

        unsigned long long m = 0ull;
#pragma unroll
        for (int i = 0; i < 4; i++) {
            const v4f q = nb[i];
            if (q.x > bx[0] && q.x < bx[6] && q.y > by[0] && q.y < by[6])
                m |= classify(q.x, q.y, bx, by);
            if (q.z > bx[0] && q.z < bx[6] && q.w > by[0] && q.w < by[6])
                m |= classify(q.z, q.w, bx, by);
        }
        // sparse union: in-box points are rare -> almost all lanes skip
        if (m) {
            const unsigned int lo = (unsigned int)m;
            const unsigned int hi = (unsigned int)(m >> 32);
            if (lo) atomicOr(&mword[sl * 2 + 0], lo);
            if (hi) atomicOr(&mword[sl * 2 + 1], hi);
        }
        {   // next-slice prefetch; lgkm-only barriers never drain it
            const int sn = (s + 1 < S2) ? s + 1 : s;
            const v4f* pf = (const v4f*)(oth + (size_t)(OBSN + sn) * NN * 2);
#pragma unroll
            for (int i = 0; i < 4; i++) nb[i] = pf[i * 512 + tid];
        }
        bar();   // B1: union mask + e_lds ready

        const unsigned long long mm =
            (unsigned long long)mword[sl * 2] |
            ((unsigned long long)mword[sl * 2 + 1] << 32);
        // zero the OTHER slot for step s+1 (its last readers were 2 barriers ago)
        if (tid == 0) { mword[(sl ^ 1) * 2] = 0u; mword[(sl ^ 1) * 2 + 1] = 0u; }

        // occupied-cell W_ih columns from LDS, spread across the quad by
        // (idx&3)==k; folds into pg via the same quad butterfly as the dots.
        float og0 = (k == 0) ? biasg[0] : 0.0f;
        float og1 = (k == 0) ? biasg[1] : 0.0f;
        float og2 = (k == 0) ? biasg[2] : 0.0f;
        float og3 = (k == 0) ? biasg[3] : 0.0f;
        {
            unsigned long long mm2 = mm;
            int idx = 0;
            while (mm2) {
                const int j = __ffsll((long long)mm2) - 1;
                mm2 &= mm2 - 1;
                if ((idx & 3) == k) {
                    const float* wc = WTl + j * WTP + u;
                    og0 += wc[0];
                    og1 += wc[128];
                    og2 += wc[256];
                    og3 += wc[384];
                }
                idx++;
            }
        }

        v2f a0 = {0.f, 0.f}, a1 = {0.f, 0.f}, a2 = {0.f, 0.f}, a3 = {0.f, 0.f};
        {
            const v4f* e4 = (const v4f*)(&e_ldsP[20 * k]);
#pragma unroll
            for (int q = 0; q < 4; q++) {
                const v4f ev = e4[q];
                const v2f el = ev.xy, eh = ev.zw;
                a0 = wie[0][2*q] * el + a0;  a0 = wie[0][2*q+1] * eh + a0;
                a1 = wie[1][2*q] * el + a1;  a1 = wie[1][2*q+1] * eh + a1;
                a2 = wie[2][2*q] * el + a2;  a2 = wie[2][2*q+1] * eh + a2;
                a3 = wie[3][2*q] * el + a3;  a3 = wie[3][2*q+1] * eh + a3;
            }
            const v4f* h4 = (const v4f*)(&hbufP[p][36 * k]);
#pragma unroll
            for (int q = 0; q < 8; q++) {
                const v4f hv = h4[q];
                const v2f hl = hv.xy, hh2 = hv.zw;
                a0 = whh[0][2*q] * hl + a0;  a0 = whh[0][2*q+1] * hh2 + a0;
                a1 = whh[1][2*q] * hl + a1;  a1 = whh[1][2*q+1] * hh2 + a1;
                a2 = whh[2][2*q] * hl + a2;  a2 = whh[2][2*q+1] * hh2 + a2;
                a3 = whh[3][2*q] * hl + a3;  a3 = whh[3][2*q+1] * hh2 + a3;
            }
        }
        float pg0 = og0 + (a0.x + a0.y);
        float pg1 = og1 + (a1.x + a1.y);
        float pg2 = og2 + (a2.x + a2.y);
        float pg3 = og3 + (a3.x + a3.y);
        pg0 = qsum(pg0); pg1 = qsum(pg1); pg2 = qsum(pg2); pg3 = qsum(pg3);

        const float gi = sigm(pg0), gf = sigm(pg1);
        const float gG = tanh_(pg2), go = sigm(pg3);
        c = gf * c + gi * gG;
        const float h = go * tanh_(c);
        if (k == 0) {
            hbufP[p ^ 1][HIDX(u)] = h;
            hist[(size_t)(S1 + s) * HID + u] = h;
        }

        float pd = (k == 0 ? won0 : (k == 1 ? won1 : 0.0f)) * h;
        pd = usum(pd);
        if (lane < 2) redn[lane][wv] = pd;
        bar();   // B2: h + redn ready

        const float n0 = hsum8(redn[0]) + bo0;
        const float n1 = hsum8(redn[1]) + bo1;
        dx = n0; dy = n1;
        pcx += n0; pcy += n1;
        if (tid < 64) {   // e for s+1; ordered vs this step's readers by B2
            float v = we0 * dx + we1 * dy + be;
            e_ldsP[EIDX(tid)] = v > 0.0f ? v : 0.0f;
        }
        p ^= 1; sl ^= 1;
    }
}

// ---------- kernel 5: parallel epilogue — out[t] = hist[t] @ W_out^T + b ----------
__global__ __launch_bounds__(64) void k_out(const float* __restrict__ hist,
                                            const float* __restrict__ W_out,
                                            const float* __restrict__ b_out,
                                            float* __restrict__ out) {
    const int t = blockIdx.x;
    const int l = threadIdx.x;
    const float h0 = hist[(size_t)t * HID + l];
    const float h1 = hist[(size_t)t * HID + 64 + l];
#pragma unroll
    for (int d = 0; d < 5; ++d) {
        float pz = W_out[d * HID + l] * h0 + W_out[d * HID + 64 + l] * h1;
#pragma unroll
        for (int off = 1; off < 64; off <<= 1) pz += __shfl_xor(pz, off);
        if (l == 0) out[t * 5 + d] = pz + b_out[d];
    }
}

// ---------- launcher ----------
extern "C" void kernel_launch(void* const* d_in, const int* in_sizes, int n_in,
                              void* d_out, int out_size, void* d_ws, size_t ws_size,
                              hipStream_t stream) {
    const float* obs   = (const float*)d_in[0];
    const float* oth   = (const float*)d_in[1];
    const float* W_emb = (const float*)d_in[2];
    const float* b_emb = (const float*)d_in[3];
    const float* W_ih  = (const float*)d_in[4];
    const float* b_ih  = (const float*)d_in[5];
    const float* W_hh  = (const float*)d_in[6];
    const float* b_hh  = (const float*)d_in[7];
    const float* W_out = (const float*)d_in[8];
    const float* b_out = (const float*)d_in[9];
    float* out = (float*)d_out;

    unsigned long long* occm = (unsigned long long*)d_ws;
    float* G1   = (float*)((char*)d_ws + 16384);
    float* WT   = (float*)((char*)d_ws + 16384 + (size_t)S1 * 512 * 4);
    float* hist = (float*)((char*)d_ws + 16384 + (size_t)S1 * 512 * 4 + (size_t)36 * 512 * 4);

    k_occ1<<<S1, 256, 0, stream>>>(obs, oth, occm);
    k_tr<<<36, 512, 0, stream>>>(W_ih, WT);
    k_g1<<<S1, 256, 0, stream>>>(obs, W_emb, b_emb, W_ih, b_ih, b_hh, occm, G1);
    k_seq<<<1, 512, 0, stream>>>(obs, oth, W_emb, b_emb, W_ih, b_ih, W_hh, b_hh,
                                 W_out, b_out, G1, WT, hist);
    k_out<<<TOTT, 64, 0, stream>>>(hist, W_out, b_out, out);
}

// Round 5
// 7279.295 us; speedup vs baseline: 1.5415x; 1.1092x over previous
//
#include <hip/hip_runtime.h>

#define NN    4096
#define OBSN  2048
#define S1    2047
#define S2    2047
#define HID   128
#define INDIM 100
#define TOTT  (S1 + S2)
#define WTP   520   // padded LDS row stride (floats) for occ-column table

typedef float v2f __attribute__((ext_vector_type(2)));
typedef float v4f __attribute__((ext_vector_type(4)));

// Barrier WITHOUT vmcnt(0) drain: cross-thread per-step dataflow is LDS-only,
// so lgkmcnt(0) suffices; global prefetches/stores stay in flight.
__device__ __forceinline__ void bar() {
    asm volatile("s_waitcnt lgkmcnt(0)\n\ts_barrier" ::: "memory");
}

__device__ __forceinline__ float sigm(float x) {
    return 1.0f / (1.0f + __expf(-x));
}
__device__ __forceinline__ float tanh_(float x) {
    float e = __expf(2.0f * x);
    return 1.0f - 2.0f / (e + 1.0f);
}

// ---- cross-lane helpers: DPP / permlane replacements for ds-based shfl ----
#define DPPF(x, ctrl) __int_as_float(__builtin_amdgcn_update_dpp(0, __float_as_int(x), (ctrl), 0xF, 0xF, true))

// sum over quad (lane^1 then lane^2) — bit-identical tree to shfl_xor(1),(2)
__device__ __forceinline__ float qsum(float x) {
    x += DPPF(x, 0xB1);   // quad_perm [1,0,3,2] = lane^1
    x += DPPF(x, 0x4E);   // quad_perm [2,3,0,1] = lane^2
    return x;
}
// sum over lane bits 2..5 (k = lane&3 groups stay separate) — identical tree
// to shfl_xor(4),(8),(16),(32)
__device__ __forceinline__ float usum(float x) {
    x += DPPF(DPPF(x, 0x141), 0x1B);    // half_mirror ∘ quad_rev = lane^4
    x += DPPF(DPPF(x, 0x140), 0x141);   // mirror ∘ half_mirror  = lane^8
    x += __int_as_float(__builtin_amdgcn_ds_swizzle(__float_as_int(x), 0x401F)); // lane^16
    auto r = __builtin_amdgcn_permlane32_swap(__float_as_int(x), __float_as_int(x), false, false);
    return __int_as_float(r[0]) + __int_as_float(r[1]);   // x[l] + x[l^32]
}

// Exact reference-semantics cell classification (strict < both sides).
__device__ __forceinline__ unsigned long long classify(float x, float y,
                                                       const float* bx, const float* by) {
    int a = 0, b = 0, c = 0, d = 0;
#pragma unroll
    for (int j = 0; j < 7; j++) {
        a += bx[j] < x;
        b += x < bx[j];
        c += by[j] < y;
        d += y < by[j];
    }
    if (a >= 1 && a <= 6 && (a + b) == 7 && c >= 1 && c <= 6 && (c + d) == 7)
        return 1ull << ((a - 1) * 6 + (c - 1));
    return 0ull;
}

__device__ __forceinline__ float hsum8(const float* p8) {
    const v4f a = ((const v4f*)p8)[0];
    const v4f b = ((const v4f*)p8)[1];
    return ((a.x + a.y) + (a.z + a.w)) + ((b.x + b.y) + (b.z + b.w));
}

// ---------- kernel 1: phase-1 occupancy masks (parallel over t) ----------
__global__ __launch_bounds__(256) void k_occ1(const float* __restrict__ obs,
                                              const float* __restrict__ oth,
                                              unsigned long long* __restrict__ occm) {
    const int t = blockIdx.x;
    const int slice = t + 1;
    const float cx = obs[slice * 2 + 0];
    const float cy = obs[slice * 2 + 1];
    const float CST[7] = {-1.5f, -1.0f, -0.5f, 0.0f, 0.5f, 1.0f, 1.5f};
    float bx[7], by[7];
#pragma unroll
    for (int j = 0; j < 7; j++) { bx[j] = CST[j] + cx; by[j] = CST[j] + cy; }

    const float2* p = (const float2*)(oth + (size_t)slice * NN * 2);
    unsigned long long m = 0ull;
#pragma unroll 4
    for (int i = 0; i < 16; i++) {
        float2 q = p[i * 256 + threadIdx.x];
        if (q.x > bx[0] && q.x < bx[6] && q.y > by[0] && q.y < by[6])
            m |= classify(q.x, q.y, bx, by);
    }
#pragma unroll
    for (int off = 32; off > 0; off >>= 1) m |= __shfl_down(m, off);
    __shared__ unsigned long long sm[4];
    if ((threadIdx.x & 63) == 0) sm[threadIdx.x >> 6] = m;
    __syncthreads();
    if (threadIdx.x == 0) occm[t] = sm[0] | sm[1] | sm[2] | sm[3];
}

// ---------- kernel 2: transpose occ columns of W_ih into [36][512] ----------
__global__ void k_tr(const float* __restrict__ W_ih, float* __restrict__ WT) {
    WT[blockIdx.x * 512 + threadIdx.x] = W_ih[threadIdx.x * INDIM + 64 + blockIdx.x];
}

// ---------- kernel 3: phase-1 gate preactivation G1[t][512] ----------
__global__ __launch_bounds__(256) void k_g1(const float* __restrict__ obs,
                                            const float* __restrict__ W_emb,
                                            const float* __restrict__ b_emb,
                                            const float* __restrict__ W_ih,
                                            const float* __restrict__ b_ih,
                                            const float* __restrict__ b_hh,
                                            const unsigned long long* __restrict__ occm,
                                            float* __restrict__ G1) {
    const int t = blockIdx.x;
    const int tid = threadIdx.x;
    __shared__ __align__(16) float e[64];
    const float d0 = obs[(t + 1) * 2 + 0] - obs[t * 2 + 0];
    const float d1 = obs[(t + 1) * 2 + 1] - obs[t * 2 + 1];
    if (tid < 64) {
        float v = W_emb[tid * 2 + 0] * d0 + W_emb[tid * 2 + 1] * d1 + b_emb[tid];
        e[tid] = v > 0.0f ? v : 0.0f;
    }
    __syncthreads();
    const unsigned long long m = occm[t];
#pragma unroll
    for (int rr = 0; rr < 2; rr++) {
        const int r = tid + rr * 256;
        const float* wr = W_ih + r * INDIM;
        float s = b_ih[r] + b_hh[r];
        float4 acc = {0.f, 0.f, 0.f, 0.f};
        const float4* w4 = (const float4*)wr;
        const float4* e4 = (const float4*)e;
#pragma unroll
        for (int q = 0; q < 16; q++) {
            float4 w = w4[q], ev = e4[q];
            acc.x += w.x * ev.x; acc.y += w.y * ev.y;
            acc.z += w.z * ev.z; acc.w += w.w * ev.w;
        }
        s += (acc.x + acc.y) + (acc.z + acc.w);
        unsigned long long mm = m;
        while (mm) {
            int j = __ffsll((long long)mm) - 1;
            mm &= mm - 1;
            s += wr[64 + j];
        }
        G1[t * 512 + r] = s;
    }
}

// ---------- kernel 4a: sequential LSTM, phase 1 (r1-verbatim math) ----------
// 512 threads = 8 waves. Thread owns unit u = wv*16 + (lane>>2), gate rows
// {u+128g}, h-cols [32k,32k+32) with k = lane&3. Quad butterfly via DPP.
// Ends by writing exact state (h[128], c[128], p1, p2) to workspace.
__global__ __launch_bounds__(512, 2) void k_ph1(const float* __restrict__ obs,
                                                const float* __restrict__ W_hh,
                                                const float* __restrict__ W_out,
                                                const float* __restrict__ b_out,
                                                const float* __restrict__ G1,
                                                float* __restrict__ hist,
                                                float* __restrict__ wsH,
                                                float* __restrict__ wsC,
                                                float* __restrict__ wsP) {
    const int tid  = threadIdx.x;
    const int wv   = tid >> 6;
    const int lane = tid & 63;
    const int u    = wv * 16 + (lane >> 2);
    const int k    = lane & 3;

    v2f whh[4][16];
#pragma unroll
    for (int g = 0; g < 4; g++) {
        const v2f* src = (const v2f*)(W_hh + (u + 128 * g) * HID + 32 * k);
#pragma unroll
        for (int j = 0; j < 16; j++) whh[g][j] = src[j];
    }

    const float won0 = W_out[u];
    const float won1 = W_out[HID + u];
    const float bo0 = b_out[0], bo1 = b_out[1];
    const float obsA0 = obs[(S1 - 1) * 2], obsA1 = obs[(S1 - 1) * 2 + 1];
    const float obsB0 = obs[S1 * 2],       obsB1 = obs[S1 * 2 + 1];

    __shared__ __align__(16) float hbuf[2][HID];
    __shared__ __align__(16) float redn[2][8];

    if (tid < HID) hbuf[0][tid] = 0.0f;
    float c = 0.0f;
    float p1x = 0.f, p1y = 0.f, p2x = 0.f, p2y = 0.f;
    int p = 0;
    __syncthreads();

    // G1 prefetch for t=0 (rows u+128g; same addr across the quad -> merged)
    v4f g1v;
    {
        const float* gp = G1 + u;
        g1v.x = gp[0]; g1v.y = gp[128]; g1v.z = gp[256]; g1v.w = gp[384];
    }

    for (int t = 0; t < S1; ++t) {
        const v4f cur = g1v;
        const int tn = (t + 1 < S1) ? t + 1 : t;
        {
            const float* gp = G1 + tn * 512 + u;
            g1v.x = gp[0]; g1v.y = gp[128]; g1v.z = gp[256]; g1v.w = gp[384];
        }

        v2f a0 = {0.f, 0.f}, a1 = {0.f, 0.f}, a2 = {0.f, 0.f}, a3 = {0.f, 0.f};
        const v4f* h4 = ((const v4f*)hbuf[p]) + k * 8;
#pragma unroll
        for (int q = 0; q < 8; q++) {
            const v4f hv = h4[q];
            const v2f hl = hv.xy, hh2 = hv.zw;
            a0 = whh[0][2*q] * hl + a0;  a0 = whh[0][2*q+1] * hh2 + a0;
            a1 = whh[1][2*q] * hl + a1;  a1 = whh[1][2*q+1] * hh2 + a1;
            a2 = whh[2][2*q] * hl + a2;  a2 = whh[2][2*q+1] * hh2 + a2;
            a3 = whh[3][2*q] * hl + a3;  a3 = whh[3][2*q+1] * hh2 + a3;
        }
        float pg0 = (a0.x + a0.y) + ((k == 0) ? cur.x : 0.0f);
        float pg1 = (a1.x + a1.y) + ((k == 0) ? cur.y : 0.0f);
        float pg2 = (a2.x + a2.y) + ((k == 0) ? cur.z : 0.0f);
        float pg3 = (a3.x + a3.y) + ((k == 0) ? cur.w : 0.0f);
        pg0 = qsum(pg0); pg1 = qsum(pg1); pg2 = qsum(pg2); pg3 = qsum(pg3);

        const float gi = sigm(pg0), gf = sigm(pg1);
        const float gG = tanh_(pg2), go = sigm(pg3);
        c = gf * c + gi * gG;
        const float h = go * tanh_(c);
        if (k == 0) {
            hbuf[p ^ 1][u] = h;
            hist[(size_t)t * HID + u] = h;    // fire-and-forget (epilogue reads)
        }

        if (t >= S1 - 2) {     // uniform branch: handoff positions to all threads
            float pd = (k == 0 ? won0 : (k == 1 ? won1 : 0.0f)) * h;
            pd = usum(pd);
            if (lane < 2) redn[lane][wv] = pd;
            bar();
            const float n0 = hsum8(redn[0]) + bo0;
            const float n1 = hsum8(redn[1]) + bo1;
            if (t == S1 - 2) { p1x = obsA0 + n0; p1y = obsA1 + n1; }
            else             { p2x = obsB0 + n0; p2y = obsB1 + n1; }
        }
        bar();
        p ^= 1;
    }

    // ---- exact state handoff ----
    if (k == 0) wsC[u] = c;
    if (tid < HID) wsH[tid] = hbuf[p][tid];   // p == S1&1 == final parity
    if (tid == 0) { wsP[0] = p1x; wsP[1] = p1y; wsP[2] = p2x; wsP[3] = p2y; }
}

// ---------- kernel 4b: sequential LSTM, phase 2 (r1-verbatim math) ----------
__global__ __launch_bounds__(512, 2) void k_ph2(const float* __restrict__ oth,
                                                const float* __restrict__ W_emb,
                                                const float* __restrict__ b_emb,
                                                const float* __restrict__ W_ih,
                                                const float* __restrict__ b_ih,
                                                const float* __restrict__ W_hh,
                                                const float* __restrict__ b_hh,
                                                const float* __restrict__ W_out,
                                                const float* __restrict__ b_out,
                                                const float* __restrict__ WT,
                                                float* __restrict__ hist,
                                                const float* __restrict__ wsH,
                                                const float* __restrict__ wsC,
                                                const float* __restrict__ wsP) {
    const int tid  = threadIdx.x;
    const int wv   = tid >> 6;
    const int lane = tid & 63;
    const int u    = wv * 16 + (lane >> 2);
    const int k    = lane & 3;

    v2f whh[4][16];
#pragma unroll
    for (int g = 0; g < 4; g++) {
        const v2f* src = (const v2f*)(W_hh + (u + 128 * g) * HID + 32 * k);
#pragma unroll
        for (int j = 0; j < 16; j++) whh[g][j] = src[j];
    }
    v2f wie[4][8];
#pragma unroll
    for (int g = 0; g < 4; g++) {
        const v2f* src = (const v2f*)(W_ih + (u + 128 * g) * INDIM + 16 * k);
#pragma unroll
        for (int j = 0; j < 8; j++) wie[g][j] = src[j];
    }
    float biasg[4];
#pragma unroll
    for (int g = 0; g < 4; g++) biasg[g] = b_ih[u + 128 * g] + b_hh[u + 128 * g];

    const float won0 = W_out[u];
    const float won1 = W_out[HID + u];
    const float bo0 = b_out[0], bo1 = b_out[1];
    float we0 = 0.f, we1 = 0.f, be = 0.f;
    if (tid < 64) { we0 = W_emb[tid * 2]; we1 = W_emb[tid * 2 + 1]; be = b_emb[tid]; }

    __shared__ __align__(16) float WTl[36 * WTP];   // occ columns, padded rows
    __shared__ __align__(16) float hbuf[2][HID];
    __shared__ __align__(16) float e_lds[64];
    __shared__ __align__(16) float redn[2][8];
    __shared__ unsigned int mword[4];               // [slot][lo/hi]

    // stage WT (global, L2-warm from k_tr) into LDS
    for (int i = tid; i < 36 * 512; i += 512)
        WTl[(i >> 9) * WTP + (i & 511)] = WT[i];
    if (tid < 4) mword[tid] = 0u;
    if (tid < HID) hbuf[0][tid] = wsH[tid];         // exact phase-1 final h
    float c = wsC[u];                               // exact phase-1 final c
    const float p1x = wsP[0], p1y = wsP[1], p2x = wsP[2], p2y = wsP[3];
    int p = 0;

    float pcx = p2x, pcy = p2y;
    float dx = p2x - p1x, dy = p2y - p1y;

    v4f nb[4];   // 8 neighbor points per thread
    {
        const v4f* s0 = (const v4f*)(oth + (size_t)OBSN * NN * 2);
#pragma unroll
        for (int i = 0; i < 4; i++) nb[i] = s0[i * 512 + tid];
    }
    if (tid < 64) {   // e for s=0; visible after first bar (B1)
        float v = we0 * dx + we1 * dy + be;
        e_lds[tid] = v > 0.0f ? v : 0.0f;
    }
    const float CST[7] = {-1.5f, -1.0f, -0.5f, 0.0f, 0.5f, 1.0f, 1.5f};
    int sl = 0;   // mask double-buffer slot
    __syncthreads();

    for (int s = 0; s < S2; ++s) {
        float bx[7], by[7];
#pragma unroll
        for (int j = 0; j < 7; j++) { bx[j] = CST[j] + pcx; by[j] = CST[j] + pcy; }

        unsigned long long m = 0ull;
#pragma unroll
        for (int i = 0; i < 4; i++) {
            const v4f q = nb[i];
            if (q.x > bx[0] && q.x < bx[6] && q.y > by[0] && q.y < by[6])
                m |= classify(q.x, q.y, bx, by);
            if (q.z > bx[0] && q.z < bx[6] && q.w > by[0] && q.w < by[6])
                m |= classify(q.z, q.w, bx, by);
        }
        // sparse union: in-box points are rare -> almost all lanes skip
        if (m) {
            const unsigned int lo = (unsigned int)m;
            const unsigned int hi = (unsigned int)(m >> 32);
            if (lo) atomicOr(&mword[sl * 2 + 0], lo);
            if (hi) atomicOr(&mword[sl * 2 + 1], hi);
        }
        {   // next-slice prefetch; lgkm-only barriers never drain it
            const int sn = (s + 1 < S2) ? s + 1 : s;
            const v4f* pf = (const v4f*)(oth + (size_t)(OBSN + sn) * NN * 2);
#pragma unroll
            for (int i = 0; i < 4; i++) nb[i] = pf[i * 512 + tid];
        }
        bar();   // B1: union mask + e_lds ready

        const unsigned long long mm =
            (unsigned long long)mword[sl * 2] |
            ((unsigned long long)mword[sl * 2 + 1] << 32);
        // zero the OTHER slot for step s+1 (its last readers were 2 barriers ago)
        if (tid == 0) { mword[(sl ^ 1) * 2] = 0u; mword[(sl ^ 1) * 2 + 1] = 0u; }

        // occupied-cell W_ih columns from LDS, spread across the quad by
        // (idx&3)==k; folds into pg via the same quad butterfly as the dots.
        float og0 = (k == 0) ? biasg[0] : 0.0f;
        float og1 = (k == 0) ? biasg[1] : 0.0f;
        float og2 = (k == 0) ? biasg[2] : 0.0f;
        float og3 = (k == 0) ? biasg[3] : 0.0f;
        {
            unsigned long long mm2 = mm;
            int idx = 0;
            while (mm2) {
                const int j = __ffsll((long long)mm2) - 1;
                mm2 &= mm2 - 1;
                if ((idx & 3) == k) {
                    const float* wc = WTl + j * WTP + u;
                    og0 += wc[0];
                    og1 += wc[128];
                    og2 += wc[256];
                    og3 += wc[384];
                }
                idx++;
            }
        }

        v2f a0 = {0.f, 0.f}, a1 = {0.f, 0.f}, a2 = {0.f, 0.f}, a3 = {0.f, 0.f};
        {
            const v4f* e4 = ((const v4f*)e_lds) + k * 4;
#pragma unroll
            for (int q = 0; q < 4; q++) {
                const v4f ev = e4[q];
                const v2f el = ev.xy, eh = ev.zw;
                a0 = wie[0][2*q] * el + a0;  a0 = wie[0][2*q+1] * eh + a0;
                a1 = wie[1][2*q] * el + a1;  a1 = wie[1][2*q+1] * eh + a1;
                a2 = wie[2][2*q] * el + a2;  a2 = wie[2][2*q+1] * eh + a2;
                a3 = wie[3][2*q] * el + a3;  a3 = wie[3][2*q+1] * eh + a3;
            }
            const v4f* h4 = ((const v4f*)hbuf[p]) + k * 8;
#pragma unroll
            for (int q = 0; q < 8; q++) {
                const v4f hv = h4[q];
                const v2f hl = hv.xy, hh2 = hv.zw;
                a0 = whh[0][2*q] * hl + a0;  a0 = whh[0][2*q+1] * hh2 + a0;
                a1 = whh[1][2*q] * hl + a1;  a1 = whh[1][2*q+1] * hh2 + a1;
                a2 = whh[2][2*q] * hl + a2;  a2 = whh[2][2*q+1] * hh2 + a2;
                a3 = whh[3][2*q] * hl + a3;  a3 = whh[3][2*q+1] * hh2 + a3;
            }
        }
        float pg0 = og0 + (a0.x + a0.y);
        float pg1 = og1 + (a1.x + a1.y);
        float pg2 = og2 + (a2.x + a2.y);
        float pg3 = og3 + (a3.x + a3.y);
        pg0 = qsum(pg0); pg1 = qsum(pg1); pg2 = qsum(pg2); pg3 = qsum(pg3);

        const float gi = sigm(pg0), gf = sigm(pg1);
        const float gG = tanh_(pg2), go = sigm(pg3);
        c = gf * c + gi * gG;
        const float h = go * tanh_(c);
        if (k == 0) {
            hbuf[p ^ 1][u] = h;
            hist[(size_t)(S1 + s) * HID + u] = h;
        }

        float pd = (k == 0 ? won0 : (k == 1 ? won1 : 0.0f)) * h;
        pd = usum(pd);
        if (lane < 2) redn[lane][wv] = pd;
        bar();   // B2: h + redn ready

        const float n0 = hsum8(redn[0]) + bo0;
        const float n1 = hsum8(redn[1]) + bo1;
        dx = n0; dy = n1;
        pcx += n0; pcy += n1;
        if (tid < 64) {   // e for s+1; ordered vs this step's readers by B2
            float v = we0 * dx + we1 * dy + be;
            e_lds[tid] = v > 0.0f ? v : 0.0f;
        }
        p ^= 1; sl ^= 1;
    }
}

// ---------- kernel 5: parallel epilogue — out[t] = hist[t] @ W_out^T + b ----------
__global__ __launch_bounds__(64) void k_out(const float* __restrict__ hist,
                                            const float* __restrict__ W_out,
                                            const float* __restrict__ b_out,
                                            float* __restrict__ out) {
    const int t = blockIdx.x;
    const int l = threadIdx.x;
    const float h0 = hist[(size_t)t * HID + l];
    const float h1 = hist[(size_t)t * HID + 64 + l];
#pragma unroll
    for (int d = 0; d < 5; ++d) {
        float pz = W_out[d * HID + l] * h0 + W_out[d * HID + 64 + l] * h1;
#pragma unroll
        for (int off = 1; off < 64; off <<= 1) pz += __shfl_xor(pz, off);
        if (l == 0) out[t * 5 + d] = pz + b_out[d];
    }
}

// ---------- launcher ----------
extern "C" void kernel_launch(void* const* d_in, const int* in_sizes, int n_in,
                              void* d_out, int out_size, void* d_ws, size_t ws_size,
                              hipStream_t stream) {
    const float* obs   = (const float*)d_in[0];
    const float* oth   = (const float*)d_in[1];
    const float* W_emb = (const float*)d_in[2];
    const float* b_emb = (const float*)d_in[3];
    const float* W_ih  = (const float*)d_in[4];
    const float* b_ih  = (const float*)d_in[5];
    const float* W_hh  = (const float*)d_in[6];
    const float* b_hh  = (const float*)d_in[7];
    const float* W_out = (const float*)d_in[8];
    const float* b_out = (const float*)d_in[9];
    float* out = (float*)d_out;

    char* wsb = (char*)d_ws;
    unsigned long long* occm = (unsigned long long*)wsb;
    float* G1   = (float*)(wsb + 16384);
    float* WT   = (float*)(wsb + 16384 + (size_t)S1 * 512 * 4);
    float* hist = (float*)(wsb + 16384 + (size_t)S1 * 512 * 4 + (size_t)36 * 512 * 4);
    float* wsH  = hist + (size_t)TOTT * HID;
    float* wsC  = wsH + HID;
    float* wsP  = wsC + HID;

    k_occ1<<<S1, 256, 0, stream>>>(obs, oth, occm);
    k_tr<<<36, 512, 0, stream>>>(W_ih, WT);
    k_g1<<<S1, 256, 0, stream>>>(obs, W_emb, b_emb, W_ih, b_ih, b_hh, occm, G1);
    k_ph1<<<1, 512, 0, stream>>>(obs, W_hh, W_out, b_out, G1, hist, wsH, wsC, wsP);
    k_ph2<<<1, 512, 0, stream>>>(oth, W_emb, b_emb, W_ih, b_ih, W_hh, b_hh,
                                 W_out, b_out, WT, hist, wsH, wsC, wsP);
    k_out<<<TOTT, 64, 0, stream>>>(hist, W_out, b_out, out);
}